// Round 3
// baseline (115.256 us; speedup 1.0000x reference)
//
#include <hip/hip_runtime.h>

#define BLOCK 256
#define LOG_2PI_F 1.8378770664093453f

// ws layout (float offsets):
//   0..7     : stats: [2] ld_sum0 [3] ld_sum1 [4] cnt0 [5] cnt1
//   16       : p_tab [2*D]   (= 0.5*exp(-2*lsd))
//   16+2D    : q_tab [2*D]   (= 2*p*mu)
//   16+4D    : b_tab [2*D]   (= -0.5*log2pi - lsd - p*mu^2)
//   PART0    : partials [gy][gx][4][256]  (plane 0=M0 1=M1 2=L0 3=L1)

__global__ __launch_bounds__(BLOCK) void k_colsum(
    const float* __restrict__ mean,
    const float* __restrict__ log_sd,
    const int*   __restrict__ target,
    const float* __restrict__ logdet,
    float* __restrict__ partials,     // ws + PART0
    float* __restrict__ stats,        // ws
    int N, int D, int rowsPerBlk)
{
    const int wave = threadIdx.x >> 6;
    const int lane = threadIdx.x & 63;
    const int col  = blockIdx.x * 256 + lane * 4;   // all 4 waves cover same 256 cols
    const int c4   = col >> 2;
    const int D4   = D >> 2;
    const int rpw  = rowsPerBlk >> 2;               // rows per wave (multiple of 16)
    const int rowBase = blockIdx.y * rowsPerBlk + wave * rpw;
    const bool colOK = (col + 3 < D);

    const float4* mean4 = reinterpret_cast<const float4*>(mean);
    const float4* lsd4  = reinterpret_cast<const float4*>(log_sd);

    float4 sM0 = make_float4(0.f,0.f,0.f,0.f);
    float4 sM1 = make_float4(0.f,0.f,0.f,0.f);
    float4 sL0 = make_float4(0.f,0.f,0.f,0.f);
    float4 sL1 = make_float4(0.f,0.f,0.f,0.f);

    for (int chunk = 0; chunk < rpw; chunk += 16) {
        const int nb = rowBase + chunk;
        // one target load per 16-row chunk, broadcast via ballot -> SGPR mask
        const int ti = nb + (lane & 15);
        const int tv = target[ti < N ? ti : N - 1];
        const unsigned long long mask = __ballot(tv != 0);
        if (!colOK) continue;
        #pragma unroll
        for (int r = 0; r < 16; ++r) {
            const int n = nb + r;
            if (n >= N) break;
            const float w1 = (float)((mask >> r) & 1ULL);
            const float w0 = 1.f - w1;
            const float4 m = mean4[(size_t)n * D4 + c4];
            const float4 l = lsd4 [(size_t)n * D4 + c4];
            sM0.x = fmaf(m.x, w0, sM0.x); sM0.y = fmaf(m.y, w0, sM0.y);
            sM0.z = fmaf(m.z, w0, sM0.z); sM0.w = fmaf(m.w, w0, sM0.w);
            sM1.x = fmaf(m.x, w1, sM1.x); sM1.y = fmaf(m.y, w1, sM1.y);
            sM1.z = fmaf(m.z, w1, sM1.z); sM1.w = fmaf(m.w, w1, sM1.w);
            sL0.x = fmaf(l.x, w0, sL0.x); sL0.y = fmaf(l.y, w0, sL0.y);
            sL0.z = fmaf(l.z, w0, sL0.z); sL0.w = fmaf(l.w, w0, sL0.w);
            sL1.x = fmaf(l.x, w1, sL1.x); sL1.y = fmaf(l.y, w1, sL1.y);
            sL1.z = fmaf(l.z, w1, sL1.z); sL1.w = fmaf(l.w, w1, sL1.w);
        }
    }

    // cross-wave LDS reduce (stride 17 -> conflict-free across 64 lanes)
    __shared__ float red[4][64][17];
    {
        float* rr = red[wave][lane];
        rr[0]=sM0.x; rr[1]=sM0.y; rr[2]=sM0.z; rr[3]=sM0.w;
        rr[4]=sM1.x; rr[5]=sM1.y; rr[6]=sM1.z; rr[7]=sM1.w;
        rr[8]=sL0.x; rr[9]=sL0.y; rr[10]=sL0.z; rr[11]=sL0.w;
        rr[12]=sL1.x; rr[13]=sL1.y; rr[14]=sL1.z; rr[15]=sL1.w;
    }
    __syncthreads();

    if (wave == 0 && colOK) {
        float v[16];
        #pragma unroll
        for (int j = 0; j < 16; ++j)
            v[j] = red[0][lane][j] + red[1][lane][j] + red[2][lane][j] + red[3][lane][j];
        // coalesced float4 stores: partial tile [4 planes][256 cols]
        float4* pt = reinterpret_cast<float4*>(
            partials + ((size_t)blockIdx.y * gridDim.x + blockIdx.x) * 1024);
        pt[(0 * 256 >> 2) + lane] = make_float4(v[0],  v[1],  v[2],  v[3]);
        pt[(1 * 256 >> 2) + lane] = make_float4(v[4],  v[5],  v[6],  v[7]);
        pt[(2 * 256 >> 2) + lane] = make_float4(v[8],  v[9],  v[10], v[11]);
        pt[(3 * 256 >> 2) + lane] = make_float4(v[12], v[13], v[14], v[15]);
    }

    // block (0,0): counts + per-class logdet sums (plain stores, no atomics)
    if (blockIdx.x == 0 && blockIdx.y == 0) {
        const int tid = threadIdx.x;
        float ld0 = 0.f, ld1 = 0.f;
        int   c0  = 0;
        for (int n = tid; n < N; n += BLOCK) {
            const int t = target[n];
            const float v = logdet[n];
            if (t == 0) { c0++; ld0 += v; } else { ld1 += v; }
        }
        __shared__ float s0[BLOCK];
        __shared__ float s1[BLOCK];
        __shared__ int   sc[BLOCK];
        s0[tid] = ld0; s1[tid] = ld1; sc[tid] = c0;
        __syncthreads();
        for (int off = BLOCK / 2; off > 0; off >>= 1) {
            if (tid < off) {
                s0[tid] += s0[tid + off];
                s1[tid] += s1[tid + off];
                sc[tid] += sc[tid + off];
            }
            __syncthreads();
        }
        if (tid == 0) {
            stats[2] = s0[0];
            stats[3] = s1[0];
            stats[4] = (float)sc[0];
            stats[5] = (float)(N - sc[0]);
        }
    }
}

// reduce partials over gy, finalize class params, build logp tables
__global__ __launch_bounds__(BLOCK) void k_reduce_finalize(
    const float* __restrict__ partials,
    const float* __restrict__ stats,
    float* __restrict__ ws,
    float* __restrict__ out,
    int D, int gx, int gy)
{
    const int idx = blockIdx.x * BLOCK + threadIdx.x;   // [0, 2*D)
    if (idx >= 2 * D) return;
    const int cls = idx / D;
    const int col = idx % D;
    const int bx  = col >> 8;
    const int cc  = col & 255;

    const float* pM = partials + cls * 256 + cc;        // plane cls
    const float* pL = partials + (2 + cls) * 256 + cc;  // plane 2+cls
    float sM = 0.f, sL = 0.f;
    for (int by = 0; by < gy; ++by) {
        const size_t base = ((size_t)by * gx + bx) * 1024;
        sM += pM[base];
        sL += pL[base];
    }
    const float cnt = stats[4 + cls];
    const float m = sM / cnt;
    const float l = sL / cnt;
    out[1 + idx]         = m;   // mus
    out[1 + 2 * D + idx] = l;   // lsds

    float* p_tab = ws + 16;
    float* q_tab = p_tab + 2 * D;
    float* b_tab = q_tab + 2 * D;
    const float p = 0.5f * expf(-2.f * l);
    p_tab[idx] = p;
    q_tab[idx] = 2.f * p * m;
    b_tab[idx] = -0.5f * LOG_2PI_F - l - p * m * m;
}

__global__ __launch_bounds__(BLOCK) void k_logp(
    const float* __restrict__ z,
    const int*   __restrict__ target,
    const float* __restrict__ ws,
    float* __restrict__ logp_out,
    int N, int D)
{
    const int wave = threadIdx.x >> 6;
    const int lane = threadIdx.x & 63;
    const int n    = blockIdx.x * 4 + wave;
    const int D4   = D >> 2;
    if (n >= N) return;

    const int t = __builtin_amdgcn_readfirstlane(target[n]);
    const float4* z4 = reinterpret_cast<const float4*>(z) + (size_t)n * D4;
    const float4* p4 = reinterpret_cast<const float4*>(ws + 16) + (size_t)t * D4;
    const float4* q4 = p4 + 2 * D4;
    const float4* b4 = q4 + 2 * D4;

    float acc = 0.f;
    #pragma unroll 4
    for (int i = lane; i < D4; i += 64) {
        const float4 zz = z4[i];
        const float4 pp = p4[i];
        const float4 qq = q4[i];
        const float4 bb = b4[i];
        float tx;
        tx = pp.x * zz.x; acc += bb.x + zz.x * (qq.x - tx);
        tx = pp.y * zz.y; acc += bb.y + zz.y * (qq.y - tx);
        tx = pp.z * zz.z; acc += bb.z + zz.z * (qq.z - tx);
        tx = pp.w * zz.w; acc += bb.w + zz.w * (qq.w - tx);
    }

    #pragma unroll
    for (int m = 32; m >= 1; m >>= 1) acc += __shfl_xor(acc, m);
    if (lane == 0) logp_out[n] = acc;
}

__global__ __launch_bounds__(1024) void k_finalize2(
    const float* __restrict__ logp,
    const int*   __restrict__ target,
    const float* __restrict__ stats,
    float* __restrict__ out,
    int N, int out_off)
{
    const int tid = threadIdx.x;
    float c0 = 0.f, c1 = 0.f;
    for (int i = tid; i < N; i += 1024) {
        const float v = logp[i];
        if (target[i] == 0) c0 += v; else c1 += v;
    }
    __shared__ float s0[1024];
    __shared__ float s1[1024];
    s0[tid] = c0; s1[tid] = c1;
    __syncthreads();
    for (int off = 512; off > 0; off >>= 1) {
        if (tid < off) {
            s0[tid] += s0[tid + off];
            s1[tid] += s1[tid + off];
        }
        __syncthreads();
    }
    if (tid == 0) {
        const float lp0 = s0[0] / stats[4];
        const float lp1 = s1[0] / stats[5];
        const float ld0 = stats[2] / stats[4];
        const float ld1 = stats[3] / stats[5];
        out[out_off]     = lp0;            // log_p_total[0]
        out[out_off + 1] = lp1;            // log_p_total[1]
        out[0] = 0.5f * ((lp0 + ld0) + (lp1 + ld1));  // prior_logprob
    }
}

extern "C" void kernel_launch(void* const* d_in, const int* in_sizes, int n_in,
                              void* d_out, int out_size, void* d_ws, size_t ws_size,
                              hipStream_t stream)
{
    const float* z      = (const float*)d_in[0];
    const float* mean   = (const float*)d_in[1];
    const float* log_sd = (const float*)d_in[2];
    const float* logdet = (const float*)d_in[3];
    const int*   target = (const int*)d_in[4];
    float* out = (float*)d_out;
    float* ws  = (float*)d_ws;

    const int N = in_sizes[3];            // 8192
    const int D = in_sizes[0] / N;        // 3072
    const int gx = (D + 255) / 256;       // 12

    // partials region after header+tables, 256-float aligned
    size_t part0 = (size_t)(16 + 6 * D);
    part0 = (part0 + 255) & ~(size_t)255;

    // pick gy (power of 2) so partials fit in ws
    int gy = 128;
    while (gy > 1 && (part0 + (size_t)gx * gy * 1024) * sizeof(float) > ws_size)
        gy >>= 1;
    const int rowsPerBlk = (N + gy - 1) / gy;   // multiple of 64 for N=8192

    float* partials = ws + part0;

    // pass 1: per-class column partial sums (no atomics)
    dim3 g1(gx, gy);
    k_colsum<<<g1, BLOCK, 0, stream>>>(mean, log_sd, target, logdet,
                                       partials, ws, N, D, rowsPerBlk);

    // reduce partials + finalize class params + build logp tables
    const int tot = 2 * D;
    k_reduce_finalize<<<(tot + BLOCK - 1) / BLOCK, BLOCK, 0, stream>>>(
        partials, ws, ws, out, D, gx, gy);

    // pass 2: per-sample logp (one wave per row)
    float* logp_out = out + 1 + 4 * D;
    k_logp<<<(N + 3) / 4, BLOCK, 0, stream>>>(z, target, ws, logp_out, N, D);

    // epilogue: class logp means + prior
    k_finalize2<<<1, 1024, 0, stream>>>(logp_out, target, ws, out,
                                        N, 1 + 4 * D + N);
}

// Round 4
// 106.184 us; speedup vs baseline: 1.0854x; 1.0854x over previous
//
#include <hip/hip_runtime.h>

#define BLOCK 256
#define LOG_2PI_F 1.8378770664093453f

// ws layout (float offsets):
//   0..7   : stats: [2] ld_sum0 [3] ld_sum1 [4] cnt0 [5] cnt1
//   16     : p_tab [2*D]   (= 0.5*exp(-2*lsd))
//   16+2D  : q_tab [2*D]   (= 2*p*mu)
//   16+4D  : b_tab [2*D]   (= -0.5*log2pi - lsd - p*mu^2)
//   PART0  : partials [2(z)][gy][gx][2][256]  (plane 0 = sumAll, plane 1 = sumC1)

__global__ __launch_bounds__(BLOCK, 4) void k_colsum(
    const float* __restrict__ mean,
    const float* __restrict__ log_sd,
    const int*   __restrict__ target,
    const float* __restrict__ logdet,
    float* __restrict__ partials,
    float* __restrict__ stats,
    int N, int D, int rowsPerBlk, int gy)
{
    const int wave = threadIdx.x >> 6;
    const int lane = threadIdx.x & 63;
    const int col  = blockIdx.x * 256 + lane * 4;   // all 4 waves cover same 256 cols
    const int c4   = col >> 2;
    const int D4   = D >> 2;
    const int rpw  = rowsPerBlk >> 2;               // rows per wave (multiple of 16)
    const int rowBase = blockIdx.y * rowsPerBlk + wave * rpw;
    const bool colOK = (col + 3 < D);

    const float4* src4 =
        reinterpret_cast<const float4*>(blockIdx.z == 0 ? mean : log_sd);

    float4 sA = make_float4(0.f, 0.f, 0.f, 0.f);   // sum over all rows
    float4 s1 = make_float4(0.f, 0.f, 0.f, 0.f);   // sum over class-1 rows

    for (int chunk = 0; chunk < rpw; chunk += 16) {
        const int nb = rowBase + chunk;
        int ti = nb + (lane & 15); if (ti > N - 1) ti = N - 1;
        const unsigned long long mask = __ballot(target[ti] != 0);
        if (!colOK) continue;
        if (nb + 16 <= N) {
            const float4* p = src4 + (size_t)nb * D4 + c4;
            #pragma unroll
            for (int b = 0; b < 2; ++b) {
                // issue 8 independent loads back-to-back (register array)
                float4 d[8];
                #pragma unroll
                for (int r = 0; r < 8; ++r)
                    d[r] = p[(size_t)(b * 8 + r) * D4];
                #pragma unroll
                for (int r = 0; r < 8; ++r) {
                    const float w1 = (float)((mask >> (b * 8 + r)) & 1ULL);
                    sA.x += d[r].x; sA.y += d[r].y;
                    sA.z += d[r].z; sA.w += d[r].w;
                    s1.x = fmaf(d[r].x, w1, s1.x);
                    s1.y = fmaf(d[r].y, w1, s1.y);
                    s1.z = fmaf(d[r].z, w1, s1.z);
                    s1.w = fmaf(d[r].w, w1, s1.w);
                }
            }
        } else {
            for (int r = 0; r < 16; ++r) {
                const int n = nb + r;
                if (n >= N) break;
                const float w1 = (float)((mask >> r) & 1ULL);
                const float4 d = src4[(size_t)n * D4 + c4];
                sA.x += d.x; sA.y += d.y; sA.z += d.z; sA.w += d.w;
                s1.x = fmaf(d.x, w1, s1.x);
                s1.y = fmaf(d.y, w1, s1.y);
                s1.z = fmaf(d.z, w1, s1.z);
                s1.w = fmaf(d.w, w1, s1.w);
            }
        }
    }

    // cross-wave LDS reduce (stride 9 floats -> 2-way bank alias, free)
    __shared__ float red[4][64][9];
    {
        float* rr = red[wave][lane];
        rr[0] = sA.x; rr[1] = sA.y; rr[2] = sA.z; rr[3] = sA.w;
        rr[4] = s1.x; rr[5] = s1.y; rr[6] = s1.z; rr[7] = s1.w;
    }
    __syncthreads();

    if (wave == 0 && colOK) {
        float v[8];
        #pragma unroll
        for (int j = 0; j < 8; ++j)
            v[j] = red[0][lane][j] + red[1][lane][j] +
                   red[2][lane][j] + red[3][lane][j];
        // coalesced float4 stores: [2 planes][256 cols] per block
        float4* pt = reinterpret_cast<float4*>(
            partials + (((size_t)blockIdx.z * gy + blockIdx.y) * gridDim.x
                        + blockIdx.x) * 512);
        pt[lane]      = make_float4(v[0], v[1], v[2], v[3]);   // sumAll
        pt[64 + lane] = make_float4(v[4], v[5], v[6], v[7]);   // sumC1
    }

    // block (0,0,0): counts + per-class logdet sums (vectorized)
    if (blockIdx.x == 0 && blockIdx.y == 0 && blockIdx.z == 0) {
        const int tid = threadIdx.x;
        float ldA = 0.f, ld1 = 0.f;
        int   c1  = 0;
        if ((N & (BLOCK * 4 - 1)) == 0) {
            const int4*   t4 = reinterpret_cast<const int4*>(target);
            const float4* l4 = reinterpret_cast<const float4*>(logdet);
            const int n4 = N >> 2;
            for (int i = tid; i < n4; i += BLOCK) {
                const int4   t = t4[i];
                const float4 v = l4[i];
                ldA += v.x + v.y + v.z + v.w;
                if (t.x) { c1++; ld1 += v.x; }
                if (t.y) { c1++; ld1 += v.y; }
                if (t.z) { c1++; ld1 += v.z; }
                if (t.w) { c1++; ld1 += v.w; }
            }
        } else {
            for (int n = tid; n < N; n += BLOCK) {
                const float v = logdet[n];
                ldA += v;
                if (target[n]) { c1++; ld1 += v; }
            }
        }
        __shared__ float sB[BLOCK], sC[BLOCK];
        __shared__ int   sI[BLOCK];
        sB[tid] = ldA; sC[tid] = ld1; sI[tid] = c1;
        __syncthreads();
        for (int off = BLOCK / 2; off > 0; off >>= 1) {
            if (tid < off) {
                sB[tid] += sB[tid + off];
                sC[tid] += sC[tid + off];
                sI[tid] += sI[tid + off];
            }
            __syncthreads();
        }
        if (tid == 0) {
            stats[2] = sB[0] - sC[0];          // ld_sum0
            stats[3] = sC[0];                  // ld_sum1
            stats[4] = (float)(N - sI[0]);     // cnt0
            stats[5] = (float)sI[0];           // cnt1
        }
    }
}

// reduce partials over gy, finalize class params, build logp tables
__global__ __launch_bounds__(BLOCK) void k_reduce_finalize(
    const float* __restrict__ partials,
    const float* __restrict__ stats,
    float* __restrict__ ws,
    float* __restrict__ out,
    int D, int gx, int gy)
{
    const int idx = blockIdx.x * BLOCK + threadIdx.x;   // [0, 2*D)
    if (idx >= 2 * D) return;
    const int cls = idx / D;
    const int col = idx - cls * D;
    const int bx  = col >> 8;
    const int cc  = col & 255;

    const size_t strideY = (size_t)gx * 512;
    const float* pm = partials + (size_t)bx * 512 + cc;       // z=0 (mean)
    const float* pl = pm + (size_t)gy * strideY;              // z=1 (log_sd)

    float mA = 0.f, m1 = 0.f, lA = 0.f, l1 = 0.f;
    for (int by = 0; by < gy; ++by) {
        const size_t o = (size_t)by * strideY;
        mA += pm[o]; m1 += pm[o + 256];
        lA += pl[o]; l1 += pl[o + 256];
    }
    const float cnt = stats[4 + cls];
    const float sm  = cls ? m1 : (mA - m1);
    const float sl  = cls ? l1 : (lA - l1);
    const float m = sm / cnt;
    const float l = sl / cnt;
    out[1 + idx]         = m;   // mus
    out[1 + 2 * D + idx] = l;   // lsds

    float* p_tab = ws + 16;
    float* q_tab = p_tab + 2 * D;
    float* b_tab = q_tab + 2 * D;
    const float p = 0.5f * expf(-2.f * l);
    p_tab[idx] = p;
    q_tab[idx] = 2.f * p * m;
    b_tab[idx] = -0.5f * LOG_2PI_F - l - p * m * m;
}

__global__ __launch_bounds__(BLOCK, 4) void k_logp(
    const float* __restrict__ z,
    const int*   __restrict__ target,
    const float* __restrict__ ws,
    float* __restrict__ logp_out,
    int N, int D)
{
    const int wave = threadIdx.x >> 6;
    const int lane = threadIdx.x & 63;
    const int n    = blockIdx.x * 4 + wave;
    const int D4   = D >> 2;
    if (n >= N) return;

    const int t = __builtin_amdgcn_readfirstlane(target[n]);
    const float4* z4 = reinterpret_cast<const float4*>(z) + (size_t)n * D4;
    const float4* p4 = reinterpret_cast<const float4*>(ws + 16) + (size_t)t * D4;
    const float4* q4 = p4 + 2 * D4;
    const float4* b4 = q4 + 2 * D4;

    float acc = 0.f;
    int i = lane;
    for (; i + 64 < D4; i += 128) {
        const float4 zz0 = z4[i];      const float4 zz1 = z4[i + 64];
        const float4 pp0 = p4[i];      const float4 pp1 = p4[i + 64];
        const float4 qq0 = q4[i];      const float4 qq1 = q4[i + 64];
        const float4 bb0 = b4[i];      const float4 bb1 = b4[i + 64];
        acc += bb0.x + zz0.x * (qq0.x - pp0.x * zz0.x);
        acc += bb0.y + zz0.y * (qq0.y - pp0.y * zz0.y);
        acc += bb0.z + zz0.z * (qq0.z - pp0.z * zz0.z);
        acc += bb0.w + zz0.w * (qq0.w - pp0.w * zz0.w);
        acc += bb1.x + zz1.x * (qq1.x - pp1.x * zz1.x);
        acc += bb1.y + zz1.y * (qq1.y - pp1.y * zz1.y);
        acc += bb1.z + zz1.z * (qq1.z - pp1.z * zz1.z);
        acc += bb1.w + zz1.w * (qq1.w - pp1.w * zz1.w);
    }
    for (; i < D4; i += 64) {
        const float4 zz = z4[i];
        const float4 pp = p4[i];
        const float4 qq = q4[i];
        const float4 bb = b4[i];
        acc += bb.x + zz.x * (qq.x - pp.x * zz.x);
        acc += bb.y + zz.y * (qq.y - pp.y * zz.y);
        acc += bb.z + zz.z * (qq.z - pp.z * zz.z);
        acc += bb.w + zz.w * (qq.w - pp.w * zz.w);
    }

    #pragma unroll
    for (int m = 32; m >= 1; m >>= 1) acc += __shfl_xor(acc, m);
    if (lane == 0) logp_out[n] = acc;
}

__global__ __launch_bounds__(1024) void k_finalize2(
    const float* __restrict__ logp,
    const int*   __restrict__ target,
    const float* __restrict__ stats,
    float* __restrict__ out,
    int N, int out_off)
{
    const int tid = threadIdx.x;
    float cA = 0.f, c1 = 0.f;
    if ((N & 4095) == 0) {
        const float4* lp4 = reinterpret_cast<const float4*>(logp);
        const int4*   t4  = reinterpret_cast<const int4*>(target);
        for (int i = tid; i < (N >> 2); i += 1024) {
            const float4 v = lp4[i];
            const int4   t = t4[i];
            cA += v.x + v.y + v.z + v.w;
            if (t.x) c1 += v.x;
            if (t.y) c1 += v.y;
            if (t.z) c1 += v.z;
            if (t.w) c1 += v.w;
        }
    } else {
        for (int i = tid; i < N; i += 1024) {
            const float v = logp[i];
            cA += v;
            if (target[i]) c1 += v;
        }
    }
    __shared__ float s0[1024];
    __shared__ float s1[1024];
    s0[tid] = cA; s1[tid] = c1;
    __syncthreads();
    for (int off = 512; off > 0; off >>= 1) {
        if (tid < off) {
            s0[tid] += s0[tid + off];
            s1[tid] += s1[tid + off];
        }
        __syncthreads();
    }
    if (tid == 0) {
        const float lp0 = (s0[0] - s1[0]) / stats[4];
        const float lp1 = s1[0] / stats[5];
        const float ld0 = stats[2] / stats[4];
        const float ld1 = stats[3] / stats[5];
        out[out_off]     = lp0;            // log_p_total[0]
        out[out_off + 1] = lp1;            // log_p_total[1]
        out[0] = 0.5f * ((lp0 + ld0) + (lp1 + ld1));  // prior_logprob
    }
}

extern "C" void kernel_launch(void* const* d_in, const int* in_sizes, int n_in,
                              void* d_out, int out_size, void* d_ws, size_t ws_size,
                              hipStream_t stream)
{
    const float* z      = (const float*)d_in[0];
    const float* mean   = (const float*)d_in[1];
    const float* log_sd = (const float*)d_in[2];
    const float* logdet = (const float*)d_in[3];
    const int*   target = (const int*)d_in[4];
    float* out = (float*)d_out;
    float* ws  = (float*)d_ws;

    const int N = in_sizes[3];            // 8192
    const int D = in_sizes[0] / N;        // 3072
    const int gx = (D + 255) / 256;       // 12

    // partials region after header+tables, 256-float aligned
    size_t part0 = (size_t)(16 + 6 * D);
    part0 = (part0 + 255) & ~(size_t)255;

    // pick gy (power of 2) so partials fit in ws
    int gy = 128;
    while (gy > 1 &&
           (part0 + (size_t)2 * gx * gy * 512) * sizeof(float) > ws_size)
        gy >>= 1;
    int rowsPerBlk = (N + gy - 1) / gy;
    rowsPerBlk = (rowsPerBlk + 63) & ~63;   // rpw multiple of 16

    float* partials = ws + part0;

    // pass 1: per-class column partial sums (z=0: mean, z=1: log_sd)
    dim3 g1(gx, gy, 2);
    k_colsum<<<g1, BLOCK, 0, stream>>>(mean, log_sd, target, logdet,
                                       partials, ws, N, D, rowsPerBlk, gy);

    // reduce partials + finalize class params + build logp tables
    const int tot = 2 * D;
    k_reduce_finalize<<<(tot + BLOCK - 1) / BLOCK, BLOCK, 0, stream>>>(
        partials, ws, ws, out, D, gx, gy);

    // pass 2: per-sample logp (one wave per row, 8 loads in flight)
    float* logp_out = out + 1 + 4 * D;
    k_logp<<<(N + 3) / 4, BLOCK, 0, stream>>>(z, target, ws, logp_out, N, D);

    // epilogue: class logp means + prior
    k_finalize2<<<1, 1024, 0, stream>>>(logp_out, target, ws, out,
                                        N, 1 + 4 * D + N);
}